// Round 7
// baseline (21735.710 us; speedup 1.0000x reference)
//
#include <hip/hip_runtime.h>

typedef short s8v __attribute__((ext_vector_type(8)));
typedef float f4v __attribute__((ext_vector_type(4)));
typedef unsigned long long ull;

#define NLAYER 6
#define HID    512
#define PROJ   128
#define SEQT   512
#define BATCH  512
#define DSTEPS 32
#define TOTS   (SEQT + DSTEPS)   // 544
#define NG     2048              // 4*H
#define BC     64                // batch rows per unit
#define NCHUNK (BATCH / BC)      // 8
#define NUNIT  (NLAYER * NCHUNK) // 48
#define RINGH  4                 // compact-h ring depth (steps)
#define PP_FLOATS 8192           // one partial slab: [128 p][64 m] f32
#define HC_SH  8192              // one compact-h slab: [128 p][64 m] bf16

// packed fragment counts (each fragment = 64 lanes * 16B = 1 KiB)
#define GFRAGS (NLAYER * 128 * 8 * 64)   // gates: [l][ntile=128][ktile=8][lane]
#define PFRAGS (NLAYER * 8 * 16 * 64)    // proj : [l][ntile=8][ktile=16][lane]
#define FFRAGS (8 * 4 * 64)              // fc   : [ntile=8][ktile=4][lane]
#define NFLAGS (2 * NUNIT)               // ubP[48] then ubH[48]

static __device__ __forceinline__ unsigned short f2b(float f) {
    union { float f; unsigned int u; } v; v.f = f;
    unsigned int r = v.u + 0x7fffu + ((v.u >> 16) & 1u);  // RNE
    return (unsigned short)(r >> 16);
}
static __device__ __forceinline__ float b2f(unsigned short s) {
    union { float f; unsigned int u; } v; v.u = ((unsigned int)s) << 16;
    return v.f;
}
static __device__ __forceinline__ float sigf(float x) {
    x = fminf(fmaxf(x, -30.f), 30.f);
    return 1.f / (1.f + __expf(-x));
}
static __device__ __forceinline__ float tanh_fast(float x) {
    x = fminf(fmaxf(x, -15.f), 15.f);
    float t = __expf(-2.f * x);
    return (1.f - t) / (1.f + t);
}
static __device__ __forceinline__ f4v mfma16(s8v a, s8v b, f4v c) {
    return __builtin_amdgcn_mfma_f32_16x16x32_bf16(a, b, c, 0, 0, 0);
}
static __device__ __forceinline__ ull ald(const ull* p) {
    return __hip_atomic_load(p, __ATOMIC_RELAXED, __HIP_MEMORY_SCOPE_AGENT);
}
static __device__ __forceinline__ void ast(ull* p, ull v) {
    __hip_atomic_store(p, v, __ATOMIC_RELAXED, __HIP_MEMORY_SCOPE_AGENT);
}
static __device__ __forceinline__ void spin_ge(unsigned* p, unsigned v) {
    while (__hip_atomic_load(p, __ATOMIC_RELAXED, __HIP_MEMORY_SCOPE_AGENT) < v)
        __builtin_amdgcn_s_sleep(2);
}
static __device__ __forceinline__ void upk(ull v, float& lo, float& hi) {
    union { ull u; float f[2]; } x; x.u = v; lo = x.f[0]; hi = x.f[1];
}

// ---------------------------------------------------------------------------
// Prepack: fp32 weights -> bf16 MFMA B-fragment-linear layout, bias sum,
// zero sync counters. (identical fragment layout to rounds 1-6, which passed)
// ---------------------------------------------------------------------------
__global__ __launch_bounds__(256) void lstm_prepack(
    const float* __restrict__ Wih, const float* __restrict__ Whh,
    const float* __restrict__ bih, const float* __restrict__ bhh,
    const float* __restrict__ Whr, const float* __restrict__ Wfc,
    const float* __restrict__ bfcin,
    unsigned short* __restrict__ gB, unsigned short* __restrict__ pB,
    unsigned short* __restrict__ fB, float* __restrict__ bsum,
    float* __restrict__ bfc, unsigned int* __restrict__ flags)
{
    int tid = blockIdx.x * 256 + threadIdx.x;

    if (tid < GFRAGS) {  // gates: cat(Wih, Whh) over K=256
        const int lane = tid & 63;
        int rest = tid >> 6;
        const int kt = rest & 7;   rest >>= 3;
        const int nt = rest & 127; rest >>= 7;
        const int l  = rest;
        const int n  = nt * 16 + (lane & 15);
        const int kb = kt * 32 + (lane >> 4) * 8;
        const float* src = (kb < 128)
            ? (Wih + ((size_t)l * NG + n) * PROJ + kb)
            : (Whh + ((size_t)l * NG + n) * PROJ + (kb - 128));
        unsigned short o[8];
        #pragma unroll
        for (int e = 0; e < 8; ++e) o[e] = f2b(src[e]);
        *(s8v*)(gB + (size_t)tid * 8) = *(const s8v*)o;
        return;
    }
    tid -= GFRAGS;
    if (tid < PFRAGS) {  // proj: Whr (p x 512), B[k][p] = Whr[p][k]
        const int lane = tid & 63;
        int rest = tid >> 6;
        const int kt = rest & 15; rest >>= 4;
        const int nt = rest & 7;  rest >>= 3;
        const int l  = rest;
        const int n  = nt * 16 + (lane & 15);
        const int kb = kt * 32 + (lane >> 4) * 8;
        const float* src = Whr + ((size_t)l * PROJ + n) * HID + kb;
        unsigned short o[8];
        #pragma unroll
        for (int e = 0; e < 8; ++e) o[e] = f2b(src[e]);
        *(s8v*)(pB + (size_t)tid * 8) = *(const s8v*)o;
        return;
    }
    tid -= PFRAGS;
    if (tid < FFRAGS) {  // fc: Wfc (128x128)
        const int lane = tid & 63;
        int rest = tid >> 6;
        const int kt = rest & 3;
        const int nt = rest >> 2;
        const int n  = nt * 16 + (lane & 15);
        const int kb = kt * 32 + (lane >> 4) * 8;
        const float* src = Wfc + (size_t)n * PROJ + kb;
        unsigned short o[8];
        #pragma unroll
        for (int e = 0; e < 8; ++e) o[e] = f2b(src[e]);
        *(s8v*)(fB + (size_t)tid * 8) = *(const s8v*)o;
        return;
    }
    tid -= FFRAGS;
    if (tid < NLAYER * NG) { bsum[tid] = bih[tid] + bhh[tid]; return; }
    tid -= NLAYER * NG;
    if (tid < PROJ) { bfc[tid] = bfcin[tid]; return; }
    tid -= PROJ;
    if (tid < NFLAGS) { flags[tid] = 0u; return; }
}

// ---------------------------------------------------------------------------
// Main: 192 blocks x 512 threads. Unit = (layer l, 64-row chunk): 4 sub-WGs.
// Gates weights persistent in 128 VGPRs/wave; proj k-split with fp32 partial
// slabs pp[unit][sub] ([128 p][64 m], depth 1). NEW vs r6: each sub reduces
// only ITS 16-row quarter of the partials and publishes the reduced h as a
// compact bf16 slab hC[unit][s%4] ([128 p][64 m]). Consumers (own h_rec,
// downstream xt, FC) read 16 KB bf16 instead of 128 KB fp32, and do no
// reduction. Two flag families: ubP (partials ready, intra-unit) and ubH
// (compact h ready). All-thread relaxed spins; release increments.
// ---------------------------------------------------------------------------
__global__ __launch_bounds__(512) void lstm_main(
    const float* __restrict__ x,               // [512][512][128] fp32
    const unsigned short* __restrict__ gB,
    const unsigned short* __restrict__ pB,
    const unsigned short* __restrict__ fB,
    const float* __restrict__ bsum,            // [6][2048]
    const float* __restrict__ bfc,             // [128]
    unsigned int* __restrict__ flags,          // ubP[48] ubH[48]
    float* __restrict__ pp,                    // [48][4][8192] f32 partials
    unsigned short* __restrict__ hC,           // [48][4][8192] bf16 compact h
    float* __restrict__ out)                   // [512][32][128] fp32
{
    const int xcd  = blockIdx.x & 7;
    const int slot = blockIdx.x >> 3;      // 0..23
    const int uo   = slot >> 2;            // 0..5
    const int sub  = slot & 3;
    const int unit = xcd * 6 + uo;         // 0..47
    const int l    = unit >> 3;
    const int bb   = (unit & 7) * BC;

    __shared__ __align__(16) unsigned short xcat[64][264];    // A=[xt | h_rec], K=256
    __shared__ __align__(16) unsigned short hfullA[64][136];  // own j-quarter h_full
    __shared__ __align__(16) unsigned short pslab[2048 * 8];  // 32 KB proj B (k-slice)

    const int tid  = threadIdx.x;
    const int lane = tid & 63;
    const int w    = tid >> 6;            // wave 0..7
    const int u    = sub * 8 + w;         // unit-wave 0..31
    const int mrow = lane & 15;
    const int kgrp = lane >> 4;
    const int cp   = tid & 127;           // consumer p
    const int chi  = tid >> 7;            // consumer m4-group 0..3

    for (int i = tid; i < 64 * 264; i += 512) ((unsigned short*)xcat)[i] = 0;

    const s8v* gfrag = (const s8v*)gB;
    const s8v* pfrag = (const s8v*)pB;
    const s8v* ffrag = (const s8v*)fB;

    // ---- persistent gates weights: 32 fragments = 128 VGPRs ----
    s8v wreg[4][8];
    #pragma unroll
    for (int g = 0; g < 4; ++g)
      #pragma unroll
      for (int kt = 0; kt < 8; ++kt)
        wreg[g][kt] = gfrag[(((size_t)l * 128 + g * 32 + u) * 8 + kt) * 64 + lane];

    float bias[4];
    #pragma unroll
    for (int g = 0; g < 4; ++g)
        bias[g] = bsum[l * NG + g * HID + u * 16 + mrow];

    // ---- proj B slab (own k-slice: all 128 p, k in [sub*128, sub*128+128)) ----
    for (int i = tid; i < 2048; i += 512) {
        const int nt = i >> 8, ktl = (i >> 6) & 3, ln = i & 63;
        ((s8v*)pslab)[i] = pfrag[(((size_t)l * 8 + nt) * 16 + sub * 4 + ktl) * 64 + ln];
    }

    f4v cst[4];
    #pragma unroll
    for (int mt = 0; mt < 4; ++mt) cst[mt] = (f4v){0.f, 0.f, 0.f, 0.f};

    unsigned int* ubP = flags;
    unsigned int* ubH = flags + NUNIT;
    float* ppu = pp + (size_t)unit * 4 * PP_FLOATS;

    __syncthreads();

    #pragma unroll 1
    for (int s = 0; s < TOTS; ++s) {
        // ---- start-of-step spins (ALL threads; no barrier needed) ----
        if (s > 0) spin_ge(&ubH[unit], 4u * (unsigned)s);               // own h(s-1)
        if (l > 0) spin_ge(&ubH[unit - NCHUNK], 4u * (unsigned)(s + 1)); // upstream h(s)
        if (l < NLAYER - 1 && s >= RINGH)
            spin_ge(&ubH[unit + NCHUNK], 4u * (unsigned)(s - RINGH + 1)); // h-ring guard

        // ---- build xcat lower (xt) ----
        if (l == 0) {
            if (s < SEQT) {
                #pragma unroll
                for (int k = 0; k < 4; ++k) {
                    const int f = k * 512 + tid;                    // float4 idx in [64][128]
                    const int m = f >> 5, q4 = f & 31;
                    const float4 v = *(const float4*)(x + (((size_t)(bb + m)) * SEQT + s) * PROJ + q4 * 4);
                    unsigned short o[4];
                    o[0] = f2b(v.x); o[1] = f2b(v.y); o[2] = f2b(v.z); o[3] = f2b(v.w);
                    *(ull*)&xcat[m][q4 * 4] = *(const ull*)o;
                }
            } else if (s == SEQT) {
                #pragma unroll
                for (int k = 0; k < 4; ++k) {
                    const int f = k * 512 + tid;
                    *(ull*)&xcat[f >> 5][(f & 31) * 4] = 0ull;
                }
            }
        } else {
            const ull* hup = (const ull*)(hC + ((size_t)(unit - NCHUNK) * RINGH + (s & 3)) * HC_SH);
            #pragma unroll
            for (int j = 0; j < 4; ++j) {
                const int m4 = chi * 4 + j;
                const ull v = ald(hup + cp * 16 + m4);
                const unsigned short* e = (const unsigned short*)&v;
                #pragma unroll
                for (int r = 0; r < 4; ++r) xcat[m4 * 4 + r][cp] = e[r];
            }
        }
        // ---- build xcat upper (h_rec = own h(s-1)) ----
        if (s > 0) {
            const ull* hme = (const ull*)(hC + ((size_t)unit * RINGH + ((s - 1) & 3)) * HC_SH);
            #pragma unroll
            for (int j = 0; j < 4; ++j) {
                const int m4 = chi * 4 + j;
                const ull v = ald(hme + cp * 16 + m4);
                const unsigned short* e = (const unsigned short*)&v;
                #pragma unroll
                for (int r = 0; r < 4; ++r) xcat[m4 * 4 + r][128 + cp] = e[r];
            }
        }
        __syncthreads();                                            // S2

        // ---- gates GEMM (weights in regs) + pointwise, mt-outer ----
        #pragma unroll
        for (int mt = 0; mt < 4; ++mt) {
            f4v a0 = (f4v){bias[0], bias[0], bias[0], bias[0]};
            f4v a1 = (f4v){bias[1], bias[1], bias[1], bias[1]};
            f4v a2 = (f4v){bias[2], bias[2], bias[2], bias[2]};
            f4v a3 = (f4v){bias[3], bias[3], bias[3], bias[3]};
            #pragma unroll
            for (int kt = 0; kt < 8; ++kt) {
                const s8v a = *(const s8v*)&xcat[mt * 16 + mrow][kt * 32 + kgrp * 8];
                a0 = mfma16(a, wreg[0][kt], a0);
                a1 = mfma16(a, wreg[1][kt], a1);
                a2 = mfma16(a, wreg[2][kt], a2);
                a3 = mfma16(a, wreg[3][kt], a3);
            }
            f4v cv = cst[mt];
            #pragma unroll
            for (int r = 0; r < 4; ++r) {
                const float cn = sigf(a1[r]) * cv[r] + sigf(a0[r]) * tanh_fast(a2[r]);
                const float hf = sigf(a3[r]) * tanh_fast(cn);
                cv[r] = cn;
                hfullA[mt * 16 + kgrp * 4 + r][w * 16 + mrow] = f2b(hf);  // local j col
            }
            cst[mt] = cv;
        }
        __syncthreads();                                            // S3

        // ---- proj GEMM, K-SPLIT; partial slab [p][m] as packed ull stores ----
        {
            f4v pacc[4];
            #pragma unroll
            for (int mt = 0; mt < 4; ++mt) pacc[mt] = (f4v){0.f, 0.f, 0.f, 0.f};
            #pragma unroll
            for (int ktl = 0; ktl < 4; ++ktl) {
                const s8v bf = ((const s8v*)pslab)[(w * 4 + ktl) * 64 + lane];
                #pragma unroll
                for (int mt = 0; mt < 4; ++mt) {
                    const s8v a = *(const s8v*)&hfullA[mt * 16 + mrow][ktl * 32 + kgrp * 8];
                    pacc[mt] = mfma16(a, bf, pacc[mt]);
                }
            }
            float* dst = ppu + (size_t)sub * PP_FLOATS + (w * 16 + mrow) * 64;
            #pragma unroll
            for (int mt = 0; mt < 4; ++mt) {
                union { float f[2]; ull u; } t0, t1;
                t0.f[0] = pacc[mt][0]; t0.f[1] = pacc[mt][1];
                t1.f[0] = pacc[mt][2]; t1.f[1] = pacc[mt][3];
                ull* p8 = (ull*)(dst + mt * 16 + kgrp * 4);
                ast(p8, t0.u); ast(p8 + 1, t1.u);
            }
        }
        __syncthreads();                                            // S4 (drains stores)
        if (tid == 0)
            __hip_atomic_fetch_add(&ubP[unit], 1u, __ATOMIC_RELEASE, __HIP_MEMORY_SCOPE_AGENT);
        spin_ge(&ubP[unit], 4u * (unsigned)(s + 1));                // all threads

        // ---- reduce own 16-row quarter -> compact bf16 h slab [p][m] ----
        {
            float r0 = 0.f, r1 = 0.f, r2 = 0.f, r3 = 0.f;
            const int foff = cp * 64 + sub * 16 + chi * 4;          // [p][m] float idx
            #pragma unroll
            for (int sb = 0; sb < 4; ++sb) {
                const ull* sp = (const ull*)(ppu + (size_t)sb * PP_FLOATS + foff);
                const ull a = ald(sp), b = ald(sp + 1);
                float x0, x1, x2, x3; upk(a, x0, x1); upk(b, x2, x3);
                r0 += x0; r1 += x1; r2 += x2; r3 += x3;
            }
            unsigned short o[4] = {f2b(r0), f2b(r1), f2b(r2), f2b(r3)};
            ull* dst = (ull*)(hC + ((size_t)unit * RINGH + (s & 3)) * HC_SH)
                       + cp * 16 + sub * 4 + chi;
            ast(dst, *(const ull*)o);
        }
        __syncthreads();                                            // S5 (drains h stores)
        if (tid == 0)
            __hip_atomic_fetch_add(&ubH[unit], 1u, __ATOMIC_RELEASE, __HIP_MEMORY_SCOPE_AGENT);

        // ---- FC head (decode, last layer): read compact h, sigf, GEMM ----
        if (l == NLAYER - 1 && s >= SEQT) {
            spin_ge(&ubH[unit], 4u * (unsigned)(s + 1));            // all threads
            const ull* hme = (const ull*)(hC + ((size_t)unit * RINGH + (s & 3)) * HC_SH);
            #pragma unroll
            for (int j = 0; j < 4; ++j) {
                const int m4 = chi * 4 + j;
                const ull v = ald(hme + cp * 16 + m4);
                const unsigned short* e = (const unsigned short*)&v;
                #pragma unroll
                for (int r = 0; r < 4; ++r)
                    hfullA[m4 * 4 + r][cp] = f2b(sigf(b2f(e[r])));
            }
            __syncthreads();                                        // S6
            const float bv = bfc[w * 16 + mrow];
            f4v facc[4];
            #pragma unroll
            for (int mt = 0; mt < 4; ++mt) facc[mt] = (f4v){bv, bv, bv, bv};
            #pragma unroll
            for (int kt = 0; kt < 4; ++kt) {
                const s8v bf = ffrag[((size_t)w * 4 + kt) * 64 + lane];
                #pragma unroll
                for (int mt = 0; mt < 4; ++mt) {
                    const s8v a = *(const s8v*)&hfullA[mt * 16 + mrow][kt * 32 + kgrp * 8];
                    facc[mt] = mfma16(a, bf, facc[mt]);
                }
            }
            const int td = s - SEQT;
            #pragma unroll
            for (int mt = 0; mt < 4; ++mt)
                #pragma unroll
                for (int r = 0; r < 4; ++r)
                    out[(((size_t)(bb + mt * 16 + kgrp * 4 + r)) * DSTEPS + td) * PROJ
                        + w * 16 + mrow] = facc[mt][r];
        }
    }
}

extern "C" void kernel_launch(void* const* d_in, const int* in_sizes, int n_in,
                              void* d_out, int out_size, void* d_ws, size_t ws_size,
                              hipStream_t stream)
{
    const float* x    = (const float*)d_in[0];
    const float* Wih  = (const float*)d_in[1];
    const float* Whh  = (const float*)d_in[2];
    const float* bih  = (const float*)d_in[3];
    const float* bhh  = (const float*)d_in[4];
    const float* Whr  = (const float*)d_in[5];
    const float* Wfc  = (const float*)d_in[6];
    const float* bfcv = (const float*)d_in[7];

    char* ws = (char*)d_ws;
    size_t off = 0;
    auto alloc = [&](size_t b) { char* p = ws + off; off += (b + 255) & ~(size_t)255; return p; };
    unsigned short* gB  = (unsigned short*)alloc((size_t)GFRAGS * 16);
    unsigned short* pB  = (unsigned short*)alloc((size_t)PFRAGS * 16);
    unsigned short* fB  = (unsigned short*)alloc((size_t)FFRAGS * 16);
    float* bsum         = (float*)alloc((size_t)NLAYER * NG * 4);
    float* bfc          = (float*)alloc((size_t)PROJ * 4);
    unsigned int* flags = (unsigned int*)alloc((size_t)NFLAGS * 4);
    float* pp           = (float*)alloc((size_t)NUNIT * 4 * PP_FLOATS * 4);
    unsigned short* hCb = (unsigned short*)alloc((size_t)NUNIT * RINGH * HC_SH * 2);
    if (off > ws_size) return;  // workspace too small; fail validation cleanly

    const int total = GFRAGS + PFRAGS + FFRAGS + NLAYER * NG + PROJ + NFLAGS;
    lstm_prepack<<<(total + 255) / 256, 256, 0, stream>>>(
        Wih, Whh, bih, bhh, Whr, Wfc, bfcv, gB, pB, fB, bsum, bfc, flags);
    lstm_main<<<NUNIT * 4, 512, 0, stream>>>(
        x, gB, pB, fB, bsum, bfc, flags, pp, hCb, (float*)d_out);
}

// Round 8
// 7682.306 us; speedup vs baseline: 2.8293x; 2.8293x over previous
//
#include <hip/hip_runtime.h>

typedef short s8v __attribute__((ext_vector_type(8)));
typedef float f4v __attribute__((ext_vector_type(4)));
typedef unsigned long long ull;

#define NLAYER 6
#define HID    512
#define PROJ   128
#define SEQT   512
#define BATCH  512
#define DSTEPS 32
#define TOTS   (SEQT + DSTEPS)   // 544
#define NG     2048              // 4*H
#define BC     64                // batch rows per unit
#define NCHUNK (BATCH / BC)      // 8
#define NUNIT  (NLAYER * NCHUNK) // 48
#define RINGP  4                 // partial-slab ring depth (steps)
#define PP_SH  8192              // one partial slab: [64 m][128 p] bf16
#define FSTRIDE 16               // flag padding: one counter per 64 B

// packed fragment counts (each fragment = 64 lanes * 16B = 1 KiB)
#define GFRAGS (NLAYER * 128 * 8 * 64)   // gates: [l][ntile=128][ktile=8][lane]
#define PFRAGS (NLAYER * 8 * 16 * 64)    // proj : [l][ntile=8][ktile=16][lane]
#define FFRAGS (8 * 4 * 64)              // fc   : [ntile=8][ktile=4][lane]
#define NFLAGS (NUNIT * FSTRIDE)

static __device__ __forceinline__ unsigned short f2b(float f) {
    union { float f; unsigned int u; } v; v.f = f;
    unsigned int r = v.u + 0x7fffu + ((v.u >> 16) & 1u);  // RNE
    return (unsigned short)(r >> 16);
}
static __device__ __forceinline__ float b2f(unsigned short s) {
    union { float f; unsigned int u; } v; v.u = ((unsigned int)s) << 16;
    return v.f;
}
static __device__ __forceinline__ float sigf(float x) {
    x = fminf(fmaxf(x, -30.f), 30.f);
    return 1.f / (1.f + __expf(-x));
}
static __device__ __forceinline__ float tanh_fast(float x) {
    x = fminf(fmaxf(x, -15.f), 15.f);
    float t = __expf(-2.f * x);
    return (1.f - t) / (1.f + t);
}
static __device__ __forceinline__ f4v mfma16(s8v a, s8v b, f4v c) {
    return __builtin_amdgcn_mfma_f32_16x16x32_bf16(a, b, c, 0, 0, 0);
}
static __device__ __forceinline__ ull ald(const ull* p) {
    return __hip_atomic_load(p, __ATOMIC_RELAXED, __HIP_MEMORY_SCOPE_AGENT);
}
static __device__ __forceinline__ void ast(ull* p, ull v) {
    __hip_atomic_store(p, v, __ATOMIC_RELAXED, __HIP_MEMORY_SCOPE_AGENT);
}
static __device__ __forceinline__ void spin_ge(unsigned* p, unsigned v) {
    while (__hip_atomic_load(p, __ATOMIC_RELAXED, __HIP_MEMORY_SCOPE_AGENT) < v)
        __builtin_amdgcn_s_sleep(2);
}
static __device__ __forceinline__ ull pk4(float a, float b, float c, float d) {
    return (ull)f2b(a) | ((ull)f2b(b) << 16) | ((ull)f2b(c) << 32) | ((ull)f2b(d) << 48);
}

// ---------------------------------------------------------------------------
// Prepack: fp32 weights -> bf16 MFMA B-fragment-linear layout, bias sum,
// zero sync counters. (identical fragment layout to rounds 1-7, which passed)
// ---------------------------------------------------------------------------
__global__ __launch_bounds__(256) void lstm_prepack(
    const float* __restrict__ Wih, const float* __restrict__ Whh,
    const float* __restrict__ bih, const float* __restrict__ bhh,
    const float* __restrict__ Whr, const float* __restrict__ Wfc,
    const float* __restrict__ bfcin,
    unsigned short* __restrict__ gB, unsigned short* __restrict__ pB,
    unsigned short* __restrict__ fB, float* __restrict__ bsum,
    float* __restrict__ bfc, unsigned int* __restrict__ flags)
{
    int tid = blockIdx.x * 256 + threadIdx.x;

    if (tid < GFRAGS) {  // gates: cat(Wih, Whh) over K=256
        const int lane = tid & 63;
        int rest = tid >> 6;
        const int kt = rest & 7;   rest >>= 3;
        const int nt = rest & 127; rest >>= 7;
        const int l  = rest;
        const int n  = nt * 16 + (lane & 15);
        const int kb = kt * 32 + (lane >> 4) * 8;
        const float* src = (kb < 128)
            ? (Wih + ((size_t)l * NG + n) * PROJ + kb)
            : (Whh + ((size_t)l * NG + n) * PROJ + (kb - 128));
        unsigned short o[8];
        #pragma unroll
        for (int e = 0; e < 8; ++e) o[e] = f2b(src[e]);
        *(s8v*)(gB + (size_t)tid * 8) = *(const s8v*)o;
        return;
    }
    tid -= GFRAGS;
    if (tid < PFRAGS) {  // proj: Whr (p x 512), frag[k][p] = Whr[p][k]
        const int lane = tid & 63;
        int rest = tid >> 6;
        const int kt = rest & 15; rest >>= 4;
        const int nt = rest & 7;  rest >>= 3;
        const int l  = rest;
        const int n  = nt * 16 + (lane & 15);
        const int kb = kt * 32 + (lane >> 4) * 8;
        const float* src = Whr + ((size_t)l * PROJ + n) * HID + kb;
        unsigned short o[8];
        #pragma unroll
        for (int e = 0; e < 8; ++e) o[e] = f2b(src[e]);
        *(s8v*)(pB + (size_t)tid * 8) = *(const s8v*)o;
        return;
    }
    tid -= PFRAGS;
    if (tid < FFRAGS) {  // fc: Wfc (128x128)
        const int lane = tid & 63;
        int rest = tid >> 6;
        const int kt = rest & 3;
        const int nt = rest >> 2;
        const int n  = nt * 16 + (lane & 15);
        const int kb = kt * 32 + (lane >> 4) * 8;
        const float* src = Wfc + (size_t)n * PROJ + kb;
        unsigned short o[8];
        #pragma unroll
        for (int e = 0; e < 8; ++e) o[e] = f2b(src[e]);
        *(s8v*)(fB + (size_t)tid * 8) = *(const s8v*)o;
        return;
    }
    tid -= FFRAGS;
    if (tid < NLAYER * NG) { bsum[tid] = bih[tid] + bhh[tid]; return; }
    tid -= NLAYER * NG;
    if (tid < PROJ) { bfc[tid] = bfcin[tid]; return; }
    tid -= PROJ;
    if (tid < NFLAGS) { flags[tid] = 0u; return; }
}

// ---------------------------------------------------------------------------
// Main: 192 blocks x 512 threads. Unit = (layer l, 64-row chunk): 4 sub-WGs.
// Gates weights persistent in 128 VGPRs/wave (AGPR-backed); proj k-split.
// vs r6 (last good): partial slabs are BF16 [64 m][128 p] (16 KB, ring depth
// 4) written as packed ull via the MFMA OPERAND SWAP -- mfma(Wfrag, hfrag)
// gives D[p-row][m-col], so each lane's 4 accs are p-consecutive. Consumers
// (own h_rec, downstream xt, FC) reduce 4 bf16 slabs with coalesced [m][p]
// ull reads -- half of r6's L3 bytes, same single-spin sync protocol
// (tid0 spins + __syncthreads, release increments, padded flags).
// ---------------------------------------------------------------------------
__global__ __launch_bounds__(512) void lstm_main(
    const float* __restrict__ x,               // [512][512][128] fp32
    const unsigned short* __restrict__ gB,
    const unsigned short* __restrict__ pB,
    const unsigned short* __restrict__ fB,
    const float* __restrict__ bsum,            // [6][2048]
    const float* __restrict__ bfc,             // [128]
    unsigned int* __restrict__ flags,          // ub[48] padded x16
    unsigned short* __restrict__ pp,           // [48][4 slot][4 sub][8192] bf16
    float* __restrict__ out)                   // [512][32][128] fp32
{
    const int xcd  = blockIdx.x & 7;
    const int slot = blockIdx.x >> 3;      // 0..23
    const int uo   = slot >> 2;            // 0..5
    const int sub  = slot & 3;
    const int unit = xcd * 6 + uo;         // 0..47
    const int l    = unit >> 3;
    const int bb   = (unit & 7) * BC;

    __shared__ __align__(16) unsigned short xcat[64][264];    // A=[xt | h_rec], K=256
    __shared__ __align__(16) unsigned short hfullA[64][136];  // own j-quarter h_full
    __shared__ __align__(16) unsigned short pslab[2048 * 8];  // 32 KB proj W (k-slice)

    const int tid  = threadIdx.x;
    const int lane = tid & 63;
    const int w    = tid >> 6;            // wave 0..7
    const int u    = sub * 8 + w;         // unit-wave 0..31
    const int mrow = lane & 15;
    const int kgrp = lane >> 4;

    for (int i = tid; i < 64 * 264; i += 512) ((unsigned short*)xcat)[i] = 0;

    const s8v* gfrag = (const s8v*)gB;
    const s8v* pfrag = (const s8v*)pB;
    const s8v* ffrag = (const s8v*)fB;

    // ---- persistent gates weights: 32 fragments = 128 VGPRs ----
    s8v wreg[4][8];
    #pragma unroll
    for (int g = 0; g < 4; ++g)
      #pragma unroll
      for (int kt = 0; kt < 8; ++kt)
        wreg[g][kt] = gfrag[(((size_t)l * 128 + g * 32 + u) * 8 + kt) * 64 + lane];

    float bias[4];
    #pragma unroll
    for (int g = 0; g < 4; ++g)
        bias[g] = bsum[l * NG + g * HID + u * 16 + mrow];

    // ---- proj W slab (own k-slice: all 128 p, k in [sub*128, sub*128+128)) ----
    for (int i = tid; i < 2048; i += 512) {
        const int nt = i >> 8, ktl = (i >> 6) & 3, ln = i & 63;
        ((s8v*)pslab)[i] = pfrag[(((size_t)l * 8 + nt) * 16 + sub * 4 + ktl) * 64 + ln];
    }

    f4v cst[4];
    #pragma unroll
    for (int mt = 0; mt < 4; ++mt) cst[mt] = (f4v){0.f, 0.f, 0.f, 0.f};

    unsigned int* ub = flags;

    __syncthreads();

    #pragma unroll 1
    for (int s = 0; s < TOTS; ++s) {
        // ---- single spin point per step (tid0 only, then barrier) ----
        if (tid == 0) {
            if (s > 0) spin_ge(&ub[unit * FSTRIDE], 4u * (unsigned)s);            // own partials(s-1)
            if (l > 0) spin_ge(&ub[(unit - NCHUNK) * FSTRIDE], 4u * (unsigned)(s + 1)); // upstream(s)
            if (l < NLAYER - 1 && s >= RINGP)
                spin_ge(&ub[(unit + NCHUNK) * FSTRIDE], 4u * (unsigned)(s - RINGP + 1)); // ring guard
        }
        __syncthreads();                                            // S1

        // ---- build xcat lower (xt) ----
        if (l == 0) {
            if (s < SEQT) {
                #pragma unroll
                for (int k = 0; k < 4; ++k) {
                    const int f = k * 512 + tid;                    // float4 idx in [64][128]
                    const int m = f >> 5, q4 = f & 31;
                    const float4 v = *(const float4*)(x + (((size_t)(bb + m)) * SEQT + s) * PROJ + q4 * 4);
                    unsigned short o[4];
                    o[0] = f2b(v.x); o[1] = f2b(v.y); o[2] = f2b(v.z); o[3] = f2b(v.w);
                    *(ull*)&xcat[m][q4 * 4] = *(const ull*)o;
                }
            } else if (s == SEQT) {
                #pragma unroll
                for (int k = 0; k < 4; ++k) {
                    const int f = k * 512 + tid;
                    *(ull*)&xcat[f >> 5][(f & 31) * 4] = 0ull;
                }
            }
        } else {
            const ull* bu = (const ull*)(pp + ((size_t)((unit - NCHUNK) * RINGP + (s & 3)) * 4) * PP_SH);
            #pragma unroll
            for (int k = 0; k < 4; ++k) {
                const int idx = k * 512 + tid;                      // ull idx in [64][128]
                const int m = idx >> 5, p4 = idx & 31;
                float r0 = 0.f, r1 = 0.f, r2 = 0.f, r3 = 0.f;
                #pragma unroll
                for (int sb = 0; sb < 4; ++sb) {
                    const ull v = ald(bu + sb * 2048 + idx);
                    r0 += b2f((unsigned short)v);
                    r1 += b2f((unsigned short)(v >> 16));
                    r2 += b2f((unsigned short)(v >> 32));
                    r3 += b2f((unsigned short)(v >> 48));
                }
                *(ull*)&xcat[m][p4 * 4] = pk4(r0, r1, r2, r3);
            }
        }
        // ---- build xcat upper (h_rec from own partials(s-1)) ----
        if (s > 0) {
            const ull* bh = (const ull*)(pp + ((size_t)(unit * RINGP + ((s - 1) & 3)) * 4) * PP_SH);
            #pragma unroll
            for (int k = 0; k < 4; ++k) {
                const int idx = k * 512 + tid;
                const int m = idx >> 5, p4 = idx & 31;
                float r0 = 0.f, r1 = 0.f, r2 = 0.f, r3 = 0.f;
                #pragma unroll
                for (int sb = 0; sb < 4; ++sb) {
                    const ull v = ald(bh + sb * 2048 + idx);
                    r0 += b2f((unsigned short)v);
                    r1 += b2f((unsigned short)(v >> 16));
                    r2 += b2f((unsigned short)(v >> 32));
                    r3 += b2f((unsigned short)(v >> 48));
                }
                *(ull*)&xcat[m][128 + p4 * 4] = pk4(r0, r1, r2, r3);
            }
        }
        __syncthreads();                                            // S2

        // ---- gates GEMM (weights in regs) + pointwise, mt-outer ----
        #pragma unroll
        for (int mt = 0; mt < 4; ++mt) {
            f4v a0 = (f4v){bias[0], bias[0], bias[0], bias[0]};
            f4v a1 = (f4v){bias[1], bias[1], bias[1], bias[1]};
            f4v a2 = (f4v){bias[2], bias[2], bias[2], bias[2]};
            f4v a3 = (f4v){bias[3], bias[3], bias[3], bias[3]};
            #pragma unroll
            for (int kt = 0; kt < 8; ++kt) {
                const s8v a = *(const s8v*)&xcat[mt * 16 + mrow][kt * 32 + kgrp * 8];
                a0 = mfma16(a, wreg[0][kt], a0);
                a1 = mfma16(a, wreg[1][kt], a1);
                a2 = mfma16(a, wreg[2][kt], a2);
                a3 = mfma16(a, wreg[3][kt], a3);
            }
            f4v cv = cst[mt];
            #pragma unroll
            for (int r = 0; r < 4; ++r) {
                const float cn = sigf(a1[r]) * cv[r] + sigf(a0[r]) * tanh_fast(a2[r]);
                const float hf = sigf(a3[r]) * tanh_fast(cn);
                cv[r] = cn;
                hfullA[mt * 16 + kgrp * 4 + r][w * 16 + mrow] = f2b(hf);  // local j col
            }
            cst[mt] = cv;
        }
        __syncthreads();                                            // S3

        // ---- proj GEMM, K-SPLIT, OPERAND-SWAPPED: D[p-row][m-col] ----
        {
            f4v pacc[4];
            #pragma unroll
            for (int mt = 0; mt < 4; ++mt) pacc[mt] = (f4v){0.f, 0.f, 0.f, 0.f};
            #pragma unroll
            for (int ktl = 0; ktl < 4; ++ktl) {
                const s8v wf = ((const s8v*)pslab)[(w * 4 + ktl) * 64 + lane];  // A: p rows
                #pragma unroll
                for (int mt = 0; mt < 4; ++mt) {
                    const s8v hf = *(const s8v*)&hfullA[mt * 16 + mrow][ktl * 32 + kgrp * 8]; // B: m cols
                    pacc[mt] = mfma16(wf, hf, pacc[mt]);
                }
            }
            // lane holds p = w*16 + kgrp*4 + r (r=0..3), m = mt*16 + mrow
            unsigned short* dst = pp + ((size_t)(unit * RINGP + (s & 3)) * 4 + sub) * PP_SH;
            #pragma unroll
            for (int mt = 0; mt < 4; ++mt) {
                ull* p8 = (ull*)(dst + (mt * 16 + mrow) * 128 + w * 16 + kgrp * 4);
                ast(p8, pk4(pacc[mt][0], pacc[mt][1], pacc[mt][2], pacc[mt][3]));
            }
        }
        __syncthreads();                                            // S4 (drains stores)
        if (tid == 0)
            __hip_atomic_fetch_add(&ub[unit * FSTRIDE], 1u, __ATOMIC_RELEASE, __HIP_MEMORY_SCOPE_AGENT);

        // ---- FC head (decode, last layer): reduce own partials(s), sigf, GEMM ----
        if (l == NLAYER - 1 && s >= SEQT) {
            if (tid == 0) spin_ge(&ub[unit * FSTRIDE], 4u * (unsigned)(s + 1));
            __syncthreads();                                        // S5
            const ull* bh = (const ull*)(pp + ((size_t)(unit * RINGP + (s & 3)) * 4) * PP_SH);
            #pragma unroll
            for (int k = 0; k < 4; ++k) {
                const int idx = k * 512 + tid;
                const int m = idx >> 5, p4 = idx & 31;
                float r0 = 0.f, r1 = 0.f, r2 = 0.f, r3 = 0.f;
                #pragma unroll
                for (int sb = 0; sb < 4; ++sb) {
                    const ull v = ald(bh + sb * 2048 + idx);
                    r0 += b2f((unsigned short)v);
                    r1 += b2f((unsigned short)(v >> 16));
                    r2 += b2f((unsigned short)(v >> 32));
                    r3 += b2f((unsigned short)(v >> 48));
                }
                *(ull*)&hfullA[m][p4 * 4] = pk4(sigf(r0), sigf(r1), sigf(r2), sigf(r3));
            }
            __syncthreads();                                        // S6
            const float bv = bfc[w * 16 + mrow];
            f4v facc[4];
            #pragma unroll
            for (int mt = 0; mt < 4; ++mt) facc[mt] = (f4v){bv, bv, bv, bv};
            #pragma unroll
            for (int kt = 0; kt < 4; ++kt) {
                const s8v bf = ffrag[((size_t)w * 4 + kt) * 64 + lane];
                #pragma unroll
                for (int mt = 0; mt < 4; ++mt) {
                    const s8v a = *(const s8v*)&hfullA[mt * 16 + mrow][kt * 32 + kgrp * 8];
                    facc[mt] = mfma16(a, bf, facc[mt]);
                }
            }
            const int td = s - SEQT;
            #pragma unroll
            for (int mt = 0; mt < 4; ++mt)
                #pragma unroll
                for (int r = 0; r < 4; ++r)
                    out[(((size_t)(bb + mt * 16 + kgrp * 4 + r)) * DSTEPS + td) * PROJ
                        + w * 16 + mrow] = facc[mt][r];
        }
    }
}

extern "C" void kernel_launch(void* const* d_in, const int* in_sizes, int n_in,
                              void* d_out, int out_size, void* d_ws, size_t ws_size,
                              hipStream_t stream)
{
    const float* x    = (const float*)d_in[0];
    const float* Wih  = (const float*)d_in[1];
    const float* Whh  = (const float*)d_in[2];
    const float* bih  = (const float*)d_in[3];
    const float* bhh  = (const float*)d_in[4];
    const float* Whr  = (const float*)d_in[5];
    const float* Wfc  = (const float*)d_in[6];
    const float* bfcv = (const float*)d_in[7];

    char* ws = (char*)d_ws;
    size_t off = 0;
    auto alloc = [&](size_t b) { char* p = ws + off; off += (b + 255) & ~(size_t)255; return p; };
    unsigned short* gB  = (unsigned short*)alloc((size_t)GFRAGS * 16);
    unsigned short* pB  = (unsigned short*)alloc((size_t)PFRAGS * 16);
    unsigned short* fB  = (unsigned short*)alloc((size_t)FFRAGS * 16);
    float* bsum         = (float*)alloc((size_t)NLAYER * NG * 4);
    float* bfc          = (float*)alloc((size_t)PROJ * 4);
    unsigned int* flags = (unsigned int*)alloc((size_t)NFLAGS * 4);
    unsigned short* pp  = (unsigned short*)alloc((size_t)NUNIT * RINGP * 4 * PP_SH * 2);
    if (off > ws_size) return;  // workspace too small; fail validation cleanly

    const int total = GFRAGS + PFRAGS + FFRAGS + NLAYER * NG + PROJ + NFLAGS;
    lstm_prepack<<<(total + 255) / 256, 256, 0, stream>>>(
        Wih, Whh, bih, bhh, Whr, Wfc, bfcv, gB, pB, fB, bsum, bfc, flags);
    lstm_main<<<NUNIT * 4, 512, 0, stream>>>(
        x, gB, pB, fB, bsum, bfc, flags, pp, (float*)d_out);
}